// Round 7
// baseline (247.409 us; speedup 1.0000x reference)
//
#include <hip/hip_runtime.h>
#include <hip/hip_bf16.h>
#include <cstring>

// Problem constants: B=2, X=96, Y=96, Z=64, C=32, K=16, LOG_PROB_SCALE=200
#define NVOX (2 * 96 * 96 * 64)
#define K_TOT 16
#define N_TILES (NVOX / 128)    // 9216 tiles of 128 voxels
#define N_WAVES (N_TILES / 2)   // 4608 waves, 2 tiles per wave

typedef __attribute__((ext_vector_type(8)))  short short8;   // 8 bf16 (A/B frag)
typedef __attribute__((ext_vector_type(16))) float f32x16;   // C/D frag
typedef __attribute__((ext_vector_type(2)))  float f32x2;

// ws layout:
//   bytes [0, 32768): A-frags bf16, ushort idx ((kc*2 + half)*64 + lane)*8 + j
//       = Linv[kc][m = lane&31][c = half*16 + (lane>>5)*8 + j]
//   floats [8192, 8704): uf[kc*32 + (lane>>5)*16 + reg] = -u_kc[(reg&3)+8*(reg>>2)+4*(lane>>5)]
//   floats [8704, 8736): pairs (h2[kc], w[kc]); h2 = log2e*(const - logdet)/200
#define WS_UF 8192
#define WS_HW 8704
#define WS_FLOATS 8736   // 34944 bytes

static __device__ __forceinline__ unsigned short f2b(float f) {
    __hip_bfloat16 h = __float2bfloat16(f);
    unsigned short u;
    __builtin_memcpy(&u, &h, 2);
    return u;
}

// Pack two f32 into a dword of two bf16 (round-half-up): 2x v_add_u32 + v_perm_b32.
static __device__ __forceinline__ int pack2_bf16(float f0, float f1) {
    unsigned a, b;
    __builtin_memcpy(&a, &f0, 4);
    __builtin_memcpy(&b, &f1, 4);
    return (int)__builtin_amdgcn_perm(b + 0x8000u, a + 0x8000u, 0x07060302u);
}

static __device__ __forceinline__ short8 cvt8(float4 lo, float4 hi) {
    int p0 = pack2_bf16(lo.x, lo.y);
    int p1 = pack2_bf16(lo.z, lo.w);
    int p2 = pack2_bf16(hi.x, hi.y);
    int p3 = pack2_bf16(hi.z, hi.w);
    int v[4] = {p0, p1, p2, p3};
    short8 r;
    __builtin_memcpy(&r, v, 16);
    return r;
}

__global__ void gmm_prep_kernel(const float* __restrict__ wb, const float* __restrict__ mb,
                                const float* __restrict__ Lb, const float* __restrict__ wf,
                                const float* __restrict__ mf, const float* __restrict__ Lf,
                                float* __restrict__ ws) {
    int k   = blockIdx.x;   // component
    int tid = threadIdx.x;  // 64 threads

    __shared__ float Lsh[1024];   // L_k row-major
    __shared__ float Lish[1024];  // Linv_k row-major (upper tri = 0)
    __shared__ float ush[32];     // u = Linv * mu

    const float* L  = (k < 8) ? (Lb + k * 1024) : (Lf + (k - 8) * 1024);
    const float* mu = (k < 8) ? (mb + k * 32)   : (mf + (k - 8) * 32);

    for (int i = tid; i < 1024; i += 64) Lsh[i] = L[i];
    __syncthreads();

    if (tid < 32) {
        int j = tid;  // solve column j: L * col = e_j
        float col[32];
#pragma unroll
        for (int i = 0; i < 32; ++i) {
            float s = (i == j) ? 1.0f : 0.0f;
#pragma unroll
            for (int m = 0; m < i; ++m) s = fmaf(-Lsh[i * 32 + m], col[m], s);
            float val = s / Lsh[i * 32 + i];
            col[i] = (i >= j) ? val : 0.0f;
        }
#pragma unroll
        for (int i = 0; i < 32; ++i) Lish[i * 32 + j] = col[i];
    }
    __syncthreads();
    if (tid < 32) {
        int d = tid;
        float s = 0.0f;
        for (int c = 0; c <= d; ++c) s = fmaf(Lish[d * 32 + c], mu[c], s);
        ush[d] = s;
    }
    __syncthreads();

    // A-fragments in MFMA 32x32x16 operand order, bf16 (RNE; prep is cold).
    unsigned short* wsA = (unsigned short*)ws;
    int m  = tid & 31;   // outdim row
    int kq = tid >> 5;   // k-half-of-8 within the MFMA's K=16
#pragma unroll
    for (int hf = 0; hf < 2; ++hf) {  // channel halves 0..15 / 16..31
        unsigned short* dst = wsA + (size_t)(((k * 2 + hf) * 64 + tid) * 8);
#pragma unroll
        for (int j = 0; j < 8; ++j)
            dst[j] = f2b(Lish[m * 32 + hf * 16 + kq * 8 + j]);
    }
    // -u in C/D fragment order
    if (tid < 32) {
        int h = tid >> 4, r = tid & 15;
        ws[WS_UF + k * 32 + tid] = -ush[(r & 3) + 8 * (r >> 2) + 4 * h];
    }
    if (tid == 0) {
        float ld = 0.0f;
        for (int i = 0; i < 32; ++i) ld += logf(Lsh[i * 32 + i]);
        const float cconst = -0.5f * 32.0f * 1.8378770664093453f;  // -C/2*log(2pi)
        const float log2e  = 1.4426950408889634f;
        ws[WS_HW + k * 2]     = (cconst - ld) * (1.0f / 200.0f) * log2e;
        ws[WS_HW + k * 2 + 1] = (k < 8) ? wb[k] : wf[k - 8];
    }
}

// 2 tiles (256 voxels) per wave, kc-outer loop shared across both tiles:
// per kc one A-frag read (2x ds_read_b128) + one Cu read (f32x16 = 4x
// ds_read_b128, loaded straight into 16 consecutive VGPRs) feeds 8
// independent MFMA-pair units -> 2x ILP, half the per-tile LDS traffic.
__global__ __launch_bounds__(256, 4) void gmm_density_kernel(
        const float* __restrict__ fm, const float* __restrict__ ws,
        float* __restrict__ out) {
    __shared__ __align__(16) float smem[WS_FLOATS];   // 34.9 KB -> 4 blocks/CU
    {
        const float4* src = (const float4*)ws;
        float4* dst = (float4*)smem;
        for (int i = threadIdx.x; i < WS_FLOATS / 4; i += 256) dst[i] = src[i];
    }
    __syncthreads();
    const unsigned short* sWf = (const unsigned short*)smem;
    const float* sUf = smem + WS_UF;
    const float* sHW = smem + WS_HW;

    const int lane = threadIdx.x & 63;
    const int c    = lane & 31;   // voxel within 32-group / D-tile column
    const int h    = lane >> 5;   // half-wave
    const int gwave = (blockIdx.x * 256 + (int)threadIdx.x) >> 6;
    size_t vbase0 = (size_t)gwave * 128;
    size_t vbase1 = (size_t)(gwave + N_WAVES) * 128;

    const float SCALE = -0.0036067376022224085f;  // -log2(e)/400

    // Load + convert B-fragments for both tiles (tile0 first, then tile1 so
    // peak raw-float liveness stays at ~64+32 regs).
    short8 B[8][2];   // [tile*4 + g][lo/hi]
#pragma unroll
    for (int t = 0; t < 2; ++t) {
        size_t vb = t ? vbase1 : vbase0;
#pragma unroll
        for (int g = 0; g < 4; ++g) {
            const float* xb = fm + (vb + g * 32 + c) * 32 + h * 8;
            float4 a0 = *(const float4*)(xb + 0);
            float4 a1 = *(const float4*)(xb + 4);
            float4 b0 = *(const float4*)(xb + 16);
            float4 b1 = *(const float4*)(xb + 20);
            B[t * 4 + g][0] = cvt8(a0, a1);
            B[t * 4 + g][1] = cvt8(b0, b1);
        }
    }

    float dens[8] = {0.f, 0.f, 0.f, 0.f, 0.f, 0.f, 0.f, 0.f};
    for (int kc = 0; kc < K_TOT; ++kc) {
        short8 Alo = *(const short8*)(sWf + ((size_t)(kc * 2 + 0) * 64 + lane) * 8);
        short8 Ahi = *(const short8*)(sWf + ((size_t)(kc * 2 + 1) * 64 + lane) * 8);
        f32x16 Cu = *(const f32x16*)(sUf + kc * 32 + h * 16);  // 4x ds_read_b128
        float h2 = sHW[kc * 2], wk = sHW[kc * 2 + 1];
#pragma unroll
        for (int g = 0; g < 8; ++g) {
            f32x16 d = __builtin_amdgcn_mfma_f32_32x32x16_bf16(Alo, B[g][0], Cu, 0, 0, 0);
            d = __builtin_amdgcn_mfma_f32_32x32x16_bf16(Ahi, B[g][1], d, 0, 0, 0);
            // q = sum of squares of the 16 C/D values; two independent
            // packed-fp32 chains, no operand copies (native f32x2 math).
            const f32x2* dp = (const f32x2*)&d;
            f32x2 acc0 = dp[0] * dp[0];
            f32x2 acc1 = dp[1] * dp[1];
#pragma unroll
            for (int r = 1; r < 4; ++r) {
                acc0 += dp[2 * r + 0] * dp[2 * r + 0];
                acc1 += dp[2 * r + 1] * dp[2 * r + 1];
            }
            f32x2 accs = acc0 + acc1;
            float p = accs[0] + accs[1];
            p += __shfl_xor(p, 32);
            dens[g] = fmaf(wk, __builtin_amdgcn_exp2f(fmaf(p, SCALE, h2)), dens[g]);
        }
    }

    // Store: half-wave h writes groups {2h, 2h+1} of each tile; zero the
    // z==63 slice (z = (g*32 + c) & 63 == 63  <=>  c==31 && g odd).
#pragma unroll
    for (int t = 0; t < 2; ++t) {
        size_t vb = t ? vbase1 : vbase0;
#pragma unroll
        for (int gg = 0; gg < 2; ++gg) {
            int g = h * 2 + gg;
            float val = dens[t * 4 + g];
            if (c == 31 && (g & 1)) val = 0.f;
            out[vb + g * 32 + c] = val;
        }
    }
}

extern "C" void kernel_launch(void* const* d_in, const int* in_sizes, int n_in,
                              void* d_out, int out_size, void* d_ws, size_t ws_size,
                              hipStream_t stream) {
    const float* fm = (const float*)d_in[0];
    const float* wb = (const float*)d_in[1];
    const float* mb = (const float*)d_in[2];
    const float* Lb = (const float*)d_in[3];
    const float* wf = (const float*)d_in[4];
    const float* mf = (const float*)d_in[5];
    const float* Lf = (const float*)d_in[6];
    float* out = (float*)d_out;
    float* ws  = (float*)d_ws;

    gmm_prep_kernel<<<K_TOT, 64, 0, stream>>>(wb, mb, Lb, wf, mf, Lf, ws);
    gmm_density_kernel<<<N_WAVES / 4, 256, 0, stream>>>(fm, ws, out);
}

// Round 8
// 240.346 us; speedup vs baseline: 1.0294x; 1.0294x over previous
//
#include <hip/hip_runtime.h>
#include <hip/hip_bf16.h>
#include <cstring>

// Problem constants: B=2, X=96, Y=96, Z=64, C=32, K=16, LOG_PROB_SCALE=200
#define NVOX (2 * 96 * 96 * 64)
#define K_TOT 16
#define N_TILES (NVOX / 128)   // 9216 tiles of 128 voxels; 1 tile per wave

typedef __attribute__((ext_vector_type(8)))  short short8;   // 8 bf16 (A/B frag)
typedef __attribute__((ext_vector_type(16))) float f32x16;   // C/D frag
typedef __attribute__((ext_vector_type(2)))  float f32x2;

// ws layout:
//   bytes [0, 32768): A-frags bf16, ushort idx ((kc*2 + half)*64 + lane)*8 + j
//       = Linv[kc][m = lane&31][c = half*16 + (lane>>5)*8 + j]
//   floats [8192, 8704): uf[kc*32 + (lane>>5)*16 + reg] = -u_kc[(reg&3)+8*(reg>>2)+4*(lane>>5)]
//   floats [8704, 8736): pairs (h2[kc], w[kc]); h2 = log2e*(const - logdet)/200
#define WS_UF 8192
#define WS_HW 8704
#define WS_FLOATS 8736   // 34944 bytes

static __device__ __forceinline__ unsigned short f2b(float f) {
    __hip_bfloat16 h = __float2bfloat16(f);
    unsigned short u;
    __builtin_memcpy(&u, &h, 2);
    return u;
}

// Pack two f32 into a dword of two bf16 (round-half-up): 2x v_add_u32 + v_perm_b32.
static __device__ __forceinline__ int pack2_bf16(float f0, float f1) {
    unsigned a, b;
    __builtin_memcpy(&a, &f0, 4);
    __builtin_memcpy(&b, &f1, 4);
    return (int)__builtin_amdgcn_perm(b + 0x8000u, a + 0x8000u, 0x07060302u);
}

static __device__ __forceinline__ short8 cvt8(float4 lo, float4 hi) {
    int p0 = pack2_bf16(lo.x, lo.y);
    int p1 = pack2_bf16(lo.z, lo.w);
    int p2 = pack2_bf16(hi.x, hi.y);
    int p3 = pack2_bf16(hi.z, hi.w);
    int v[4] = {p0, p1, p2, p3};
    short8 r;
    __builtin_memcpy(&r, v, 16);
    return r;
}

__global__ void gmm_prep_kernel(const float* __restrict__ wb, const float* __restrict__ mb,
                                const float* __restrict__ Lb, const float* __restrict__ wf,
                                const float* __restrict__ mf, const float* __restrict__ Lf,
                                float* __restrict__ ws) {
    int k   = blockIdx.x;   // component
    int tid = threadIdx.x;  // 64 threads

    __shared__ float Lsh[1024];   // L_k row-major
    __shared__ float Lish[1024];  // Linv_k row-major (upper tri = 0)
    __shared__ float ush[32];     // u = Linv * mu

    const float* L  = (k < 8) ? (Lb + k * 1024) : (Lf + (k - 8) * 1024);
    const float* mu = (k < 8) ? (mb + k * 32)   : (mf + (k - 8) * 32);

    for (int i = tid; i < 1024; i += 64) Lsh[i] = L[i];
    __syncthreads();

    if (tid < 32) {
        int j = tid;  // solve column j: L * col = e_j
        float col[32];
#pragma unroll
        for (int i = 0; i < 32; ++i) {
            float s = (i == j) ? 1.0f : 0.0f;
#pragma unroll
            for (int m = 0; m < i; ++m) s = fmaf(-Lsh[i * 32 + m], col[m], s);
            float val = s / Lsh[i * 32 + i];
            col[i] = (i >= j) ? val : 0.0f;
        }
#pragma unroll
        for (int i = 0; i < 32; ++i) Lish[i * 32 + j] = col[i];
    }
    __syncthreads();
    if (tid < 32) {
        int d = tid;
        float s = 0.0f;
        for (int c = 0; c <= d; ++c) s = fmaf(Lish[d * 32 + c], mu[c], s);
        ush[d] = s;
    }
    __syncthreads();

    // A-fragments in MFMA 32x32x16 operand order, bf16 (RNE; prep is cold).
    unsigned short* wsA = (unsigned short*)ws;
    int m  = tid & 31;   // outdim row
    int kq = tid >> 5;   // k-half-of-8 within the MFMA's K=16
#pragma unroll
    for (int hf = 0; hf < 2; ++hf) {  // channel halves 0..15 / 16..31
        unsigned short* dst = wsA + (size_t)(((k * 2 + hf) * 64 + tid) * 8);
#pragma unroll
        for (int j = 0; j < 8; ++j)
            dst[j] = f2b(Lish[m * 32 + hf * 16 + kq * 8 + j]);
    }
    // -u in C/D fragment order
    if (tid < 32) {
        int h = tid >> 4, r = tid & 15;
        ws[WS_UF + k * 32 + tid] = -ush[(r & 3) + 8 * (r >> 2) + 4 * h];
    }
    if (tid == 0) {
        float ld = 0.0f;
        for (int i = 0; i < 32; ++i) ld += logf(Lsh[i * 32 + i]);
        const float cconst = -0.5f * 32.0f * 1.8378770664093453f;  // -C/2*log(2pi)
        const float log2e  = 1.4426950408889634f;
        ws[WS_HW + k * 2]     = (cconst - ld) * (1.0f / 200.0f) * log2e;
        ws[WS_HW + k * 2 + 1] = (k < 8) ? wb[k] : wf[k - 8];
    }
}

// 1 tile (128 voxels) per wave; launch_bounds(256,3) -> ~170-VGPR budget so
// the full live set (B 32 + four in-flight d-frags 64 + Cu 16 + A 8 + dens 4
// + addr) fits with no AGPR round-trips (r5 counters: VALUBusy 4.4x source
// need at VGPR_Count=56; r7 showed 2-tile/wave re-blows the 128 budget).
__global__ __launch_bounds__(256, 3) void gmm_density_kernel(
        const float* __restrict__ fm, const float* __restrict__ ws,
        float* __restrict__ out) {
    __shared__ __align__(16) float smem[WS_FLOATS];   // 34.9 KB
    {
        const float4* src = (const float4*)ws;
        float4* dst = (float4*)smem;
        for (int i = threadIdx.x; i < WS_FLOATS / 4; i += 256) dst[i] = src[i];
    }
    __syncthreads();
    const unsigned short* sWf = (const unsigned short*)smem;
    const float* sUf = smem + WS_UF;
    const float* sHW = smem + WS_HW;

    const int lane = threadIdx.x & 63;
    const int c    = lane & 31;   // voxel within 32-group / D-tile column
    const int h    = lane >> 5;   // half-wave
    const int tile = (blockIdx.x * 256 + (int)threadIdx.x) >> 6;  // 1 tile/wave
    size_t vbase = (size_t)tile * 128;

    const float SCALE = -0.0036067376022224085f;  // -log2(e)/400

    // Load + convert B-fragments: 4 groups of 32 voxels, channel halves per h.
    short8 Blo[4], Bhi[4];
#pragma unroll
    for (int g = 0; g < 4; ++g) {
        const float* xb = fm + (vbase + g * 32 + c) * 32 + h * 8;
        float4 a0 = *(const float4*)(xb + 0);
        float4 a1 = *(const float4*)(xb + 4);
        float4 b0 = *(const float4*)(xb + 16);
        float4 b1 = *(const float4*)(xb + 20);
        Blo[g] = cvt8(a0, a1);
        Bhi[g] = cvt8(b0, b1);
    }

    float dens[4] = {0.f, 0.f, 0.f, 0.f};
    for (int kc = 0; kc < K_TOT; ++kc) {
        short8 Alo = *(const short8*)(sWf + ((size_t)(kc * 2 + 0) * 64 + lane) * 8);
        short8 Ahi = *(const short8*)(sWf + ((size_t)(kc * 2 + 1) * 64 + lane) * 8);
        f32x16 Cu = *(const f32x16*)(sUf + kc * 32 + h * 16);  // 4x ds_read_b128
        float h2 = sHW[kc * 2], wk = sHW[kc * 2 + 1];
#pragma unroll
        for (int g = 0; g < 4; ++g) {
            f32x16 d = __builtin_amdgcn_mfma_f32_32x32x16_bf16(Alo, Blo[g], Cu, 0, 0, 0);
            d = __builtin_amdgcn_mfma_f32_32x32x16_bf16(Ahi, Bhi[g], d, 0, 0, 0);
            // q = sum of squares of the 16 C/D values; two independent
            // packed-fp32 chains, no operand copies (native f32x2 math).
            const f32x2* dp = (const f32x2*)&d;
            f32x2 acc0 = dp[0] * dp[0];
            f32x2 acc1 = dp[1] * dp[1];
#pragma unroll
            for (int r = 1; r < 4; ++r) {
                acc0 += dp[2 * r + 0] * dp[2 * r + 0];
                acc1 += dp[2 * r + 1] * dp[2 * r + 1];
            }
            f32x2 accs = acc0 + acc1;
            float p = accs[0] + accs[1];
            p += __shfl_xor(p, 32);
            dens[g] = fmaf(wk, __builtin_amdgcn_exp2f(fmaf(p, SCALE, h2)), dens[g]);
        }
    }

    // Store: half-wave h writes groups {2h, 2h+1}; zero the z==63 slice
    // (z = (g*32 + c) & 63 == 63  <=>  c==31 && g odd).
#pragma unroll
    for (int gg = 0; gg < 2; ++gg) {
        int g = h * 2 + gg;
        float val = dens[g];
        if (c == 31 && (g & 1)) val = 0.f;
        out[vbase + g * 32 + c] = val;
    }
}

extern "C" void kernel_launch(void* const* d_in, const int* in_sizes, int n_in,
                              void* d_out, int out_size, void* d_ws, size_t ws_size,
                              hipStream_t stream) {
    const float* fm = (const float*)d_in[0];
    const float* wb = (const float*)d_in[1];
    const float* mb = (const float*)d_in[2];
    const float* Lb = (const float*)d_in[3];
    const float* wf = (const float*)d_in[4];
    const float* mf = (const float*)d_in[5];
    const float* Lf = (const float*)d_in[6];
    float* out = (float*)d_out;
    float* ws  = (float*)d_ws;

    gmm_prep_kernel<<<K_TOT, 64, 0, stream>>>(wb, mb, Lb, wf, mf, Lf, ws);
    gmm_density_kernel<<<N_TILES / 4, 256, 0, stream>>>(fm, ws, out);
}